// Round 1
// baseline (653.775 us; speedup 1.0000x reference)
//
#include <hip/hip_runtime.h>

#define NA 15
#define GH 34
#define GW 34
#define SP (GH*GW)          // 1156
#define NB (SP*NA)          // 17340
#define MAXC 5000
#define TOPN 300
#define NW64 79             // ceil(MAXC/64)
#define THRESH_OBJ 0.2f
#define NMS_T 0.7f

__constant__ float c_aw[NA] = {45.3f,32.0f,22.6f,90.5f,64.0f,45.3f,181.0f,128.0f,90.5f,271.5f,192.0f,135.8f,362.0f,256.0f,181.0f};
__constant__ float c_ah[NA] = {22.6f,32.0f,45.3f,45.3f,64.0f,90.5f,90.5f,128.0f,181.0f,135.8f,192.0f,271.5f,181.0f,256.0f,362.0f};

// ---------------- decode: anchors + deltas -> clipped proposals, keep mask ----------------
__global__ __launch_bounds__(256) void k_decode(
    const float* __restrict__ cls, const float* __restrict__ pred,
    const int* __restrict__ iminfo, const float* __restrict__ mean,
    const float* __restrict__ stdv, float* __restrict__ boxes,
    float* __restrict__ mscore, int* __restrict__ cnt) {
#pragma clang fp contract(off)
  int r = blockIdx.x * 256 + threadIdx.x;
  if (r >= NB) return;
  int n = r % NA;
  int p = r / NA;       // p = h*GW + w
  int w = p % GW;
  int h = p / GW;

  float score = cls[(NA + n) * SP + p];             // channel NA+n, spatial p

  float d0 = pred[(n*4+0)*SP + p] * stdv[0] + mean[0];
  float d1 = pred[(n*4+1)*SP + p] * stdv[1] + mean[1];
  float d2 = pred[(n*4+2)*SP + p] * stdv[2] + mean[2];
  float d3 = pred[(n*4+3)*SP + p] * stdv[3] + mean[3];

  float aw = c_aw[n], ah = c_ah[n];
  float sx = (float)(w * 16);
  float sy = (float)(h * 16);
  float xmin = -0.5f * (aw - 1.0f) + sx;
  float ymin = -0.5f * (ah - 1.0f) + sy;
  float xmax =  0.5f * (aw - 1.0f) + sx;
  float ymax =  0.5f * (ah - 1.0f) + sy;

  float widths  = xmax - xmin + 1.0f;
  float heights = ymax - ymin + 1.0f;
  float ctrx = xmin + 0.5f * (widths - 1.0f);
  float ctry = ymin + 0.5f * (heights - 1.0f);

  float pcx = d0 * widths + ctrx;
  float pcy = d1 * heights + ctry;
  float pw = expf(d2) * widths;
  float ph = expf(d3) * heights;

  float x1 = pcx - 0.5f * (pw - 1.0f);
  float y1 = pcy - 0.5f * (ph - 1.0f);
  float x2 = pcx + 0.5f * (pw - 1.0f);
  float y2 = pcy + 0.5f * (ph - 1.0f);

  float ow = (float)iminfo[1] - 1.0f;
  float oh = (float)iminfo[0] - 1.0f;
  x1 = fminf(fmaxf(x1, 0.0f), ow);
  x2 = fminf(fmaxf(x2, 0.0f), ow);
  y1 = fminf(fmaxf(y1, 0.0f), oh);
  y2 = fminf(fmaxf(y2, 0.0f), oh);

  float ws = x2 - x1 + 1.0f;
  float hs = y2 - y1 + 1.0f;
  bool keep = (score > THRESH_OBJ) && (ws >= 6.0f) && (hs >= 6.0f);

  boxes[r*4+0] = x1;
  boxes[r*4+1] = y1;
  boxes[r*4+2] = x2;
  boxes[r*4+3] = y2;
  mscore[r] = keep ? score : -1.0f;
  if (keep) atomicAdd(cnt, 1);
}

// ---------------- rank-by-counting: exact top-k order with (score desc, idx asc) ----------------
__global__ __launch_bounds__(64) void k_rank(const float* __restrict__ mscore,
    const float* __restrict__ boxes, float* __restrict__ sboxes) {
  constexpr int TILE = 5780;                 // 3 * 5780 = 17340, divisible by 4
  __shared__ float sm[TILE];
  int tid = threadIdx.x;
  int i = blockIdx.x * 64 + tid;
  float mi = (i < NB) ? mscore[i] : -2.0f;
  bool active = (i < NB) && (mi > THRESH_OBJ);
  int rank = 0;
  for (int t0 = 0; t0 < NB; t0 += TILE) {
    const float4* g4 = (const float4*)(mscore + t0);
    float4* s4 = (float4*)sm;
    for (int j = tid; j < TILE/4; j += 64) s4[j] = g4[j];
    __syncthreads();
    if (active) {
      const float4* sm4 = (const float4*)sm;
#pragma unroll 4
      for (int j4 = 0; j4 < TILE/4; ++j4) {
        float4 v = sm4[j4];
        int jb = t0 + j4*4;
        rank += (v.x > mi) ? 1 : 0;
        rank += (v.x == mi && (jb+0) < i) ? 1 : 0;
        rank += (v.y > mi) ? 1 : 0;
        rank += (v.y == mi && (jb+1) < i) ? 1 : 0;
        rank += (v.z > mi) ? 1 : 0;
        rank += (v.z == mi && (jb+2) < i) ? 1 : 0;
        rank += (v.w > mi) ? 1 : 0;
        rank += (v.w == mi && (jb+3) < i) ? 1 : 0;
      }
    }
    __syncthreads();
  }
  if (active && rank < MAXC) {
    ((float4*)sboxes)[rank] = ((const float4*)boxes)[i];
  }
}

// ---------------- pairwise IoU bitmask (full grid; lower triangle writes zeros) ----------------
__global__ __launch_bounds__(64) void k_iou(const float* __restrict__ sboxes,
    const int* __restrict__ cnt, unsigned long long* __restrict__ mask) {
#pragma clang fp contract(off)
  int N = min(*cnt, MAXC);
  int bi = blockIdx.x, bj = blockIdx.y;
  int t = threadIdx.x;
  int i = bi * 64 + t;
  if (bj < bi) {                      // lower triangle: just zero-fill (ws is poisoned)
    if (i < N) mask[(size_t)i * NW64 + bj] = 0ULL;
    return;
  }
  if (bi * 64 >= N) return;
  __shared__ float4 jb[64];
  int j0 = bj * 64;
  if (j0 + t < N) jb[t] = ((const float4*)sboxes)[j0 + t];
  __syncthreads();
  if (i >= N) return;
  float4 a = ((const float4*)sboxes)[i];
  float areaA = (a.z - a.x + 1.0f) * (a.w - a.y + 1.0f);
  unsigned long long word = 0;
  int jmax = min(64, N - j0);
  for (int jj = 0; jj < jmax; ++jj) {
    int j = j0 + jj;
    if (j <= i) continue;
    float4 b = jb[jj];
    float iw = fminf(a.z, b.z) - fmaxf(a.x, b.x) + 1.0f;
    float ih = fminf(a.w, b.w) - fmaxf(a.y, b.y) + 1.0f;
    iw = fmaxf(iw, 0.0f);
    ih = fmaxf(ih, 0.0f);
    float inter = iw * ih;
    float areaB = (b.z - b.x + 1.0f) * (b.w - b.y + 1.0f);
    float iou = inter / (areaA + areaB - inter);
    if (iou > NMS_T) word |= (1ULL << jj);
  }
  mask[(size_t)i * NW64 + bj] = word;
}

// ---------------- serial greedy NMS scan (1 wave), writes first 300 kept rows ----------------
__global__ __launch_bounds__(64) void k_nms(const float* __restrict__ sboxes,
    const unsigned long long* __restrict__ mask, const int* __restrict__ cnt,
    float* __restrict__ out) {
  __shared__ unsigned long long remv[NW64];
  int t = threadIdx.x;
  remv[t] = 0ULL;
  if (t + 64 < NW64) remv[t + 64] = 0ULL;
  __syncthreads();
  int N = min(*cnt, MAXC);
  int kept = 0;
  for (int i = 0; i < N; ++i) {
    const unsigned long long* row = mask + (size_t)i * NW64;
    // prefetch mask row (issues before the dependent remv check)
    unsigned long long a = row[t];
    unsigned long long b = (t + 64 < NW64) ? row[t + 64] : 0ULL;
    unsigned long long wv = remv[i >> 6];
    if (!((wv >> (i & 63)) & 1ULL)) {
      if (t < 4) out[kept * 5 + 1 + t] = sboxes[i * 4 + t];
      ++kept;
      if (kept >= TOPN) break;
      remv[t] |= a;
      if (t + 64 < NW64) remv[t + 64] |= b;
    }
    __syncthreads();
  }
}

extern "C" void kernel_launch(void* const* d_in, const int* in_sizes, int n_in,
                              void* d_out, int out_size, void* d_ws, size_t ws_size,
                              hipStream_t stream) {
  const float* cls  = (const float*)d_in[0];
  const float* pred = (const float*)d_in[1];
  const int*   imi  = (const int*)d_in[2];
  const float* mean = (const float*)d_in[3];
  const float* stdv = (const float*)d_in[4];
  float* out = (float*)d_out;

  char* ws = (char*)d_ws;
  float* boxes  = (float*)(ws);                        // NB*4 floats   = 277440 B
  float* mscore = (float*)(ws + 277440);               // NB floats     = 69360 B
  float* sboxes = (float*)(ws + 346800);               // MAXC*4 floats = 80000 B
  int*   cnt    = (int*)(ws + 426800);                 // 4 B (+pad)
  unsigned long long* mask = (unsigned long long*)(ws + 426816); // MAXC*NW64*8 = 3160000 B

  hipMemsetAsync(cnt, 0, sizeof(int), stream);
  hipMemsetAsync(d_out, 0, (size_t)out_size * sizeof(float), stream);

  k_decode<<<(NB + 255) / 256, 256, 0, stream>>>(cls, pred, imi, mean, stdv, boxes, mscore, cnt);
  k_rank<<<(NB + 63) / 64, 64, 0, stream>>>(mscore, boxes, sboxes);
  dim3 giou(NW64, NW64);
  k_iou<<<giou, 64, 0, stream>>>(sboxes, cnt, mask);
  k_nms<<<1, 64, 0, stream>>>(sboxes, mask, cnt, out);
}

// Round 2
// 205.059 us; speedup vs baseline: 3.1882x; 3.1882x over previous
//
#include <hip/hip_runtime.h>

#define NA 15
#define GH 34
#define GW 34
#define SP (GH*GW)          // 1156
#define NB (SP*NA)          // 17340
#define MAXC 5000
#define TOPN 300
#define NW64 79             // ceil(MAXC/64)
#define THRESH_OBJ 0.2f
#define NMS_T 0.7f

__constant__ float c_aw[NA] = {45.3f,32.0f,22.6f,90.5f,64.0f,45.3f,181.0f,128.0f,90.5f,271.5f,192.0f,135.8f,362.0f,256.0f,181.0f};
__constant__ float c_ah[NA] = {22.6f,32.0f,45.3f,45.3f,64.0f,90.5f,90.5f,128.0f,181.0f,135.8f,192.0f,271.5f,181.0f,256.0f,362.0f};

// ---------------- decode: anchors + deltas -> clipped proposals, keep mask ----------------
__global__ __launch_bounds__(256) void k_decode(
    const float* __restrict__ cls, const float* __restrict__ pred,
    const int* __restrict__ iminfo, const float* __restrict__ mean,
    const float* __restrict__ stdv, float* __restrict__ boxes,
    float* __restrict__ mscore, int* __restrict__ cnt, int* __restrict__ rank) {
#pragma clang fp contract(off)
  int r = blockIdx.x * 256 + threadIdx.x;
  if (r >= NB) return;
  rank[r] = 0;
  int n = r % NA;
  int p = r / NA;       // p = h*GW + w
  int w = p % GW;
  int h = p / GW;

  float score = cls[(NA + n) * SP + p];             // channel NA+n, spatial p

  float d0 = pred[(n*4+0)*SP + p] * stdv[0] + mean[0];
  float d1 = pred[(n*4+1)*SP + p] * stdv[1] + mean[1];
  float d2 = pred[(n*4+2)*SP + p] * stdv[2] + mean[2];
  float d3 = pred[(n*4+3)*SP + p] * stdv[3] + mean[3];

  float aw = c_aw[n], ah = c_ah[n];
  float sx = (float)(w * 16);
  float sy = (float)(h * 16);
  float xmin = -0.5f * (aw - 1.0f) + sx;
  float ymin = -0.5f * (ah - 1.0f) + sy;
  float xmax =  0.5f * (aw - 1.0f) + sx;
  float ymax =  0.5f * (ah - 1.0f) + sy;

  float widths  = xmax - xmin + 1.0f;
  float heights = ymax - ymin + 1.0f;
  float ctrx = xmin + 0.5f * (widths - 1.0f);
  float ctry = ymin + 0.5f * (heights - 1.0f);

  float pcx = d0 * widths + ctrx;
  float pcy = d1 * heights + ctry;
  float pw = expf(d2) * widths;
  float ph = expf(d3) * heights;

  float x1 = pcx - 0.5f * (pw - 1.0f);
  float y1 = pcy - 0.5f * (ph - 1.0f);
  float x2 = pcx + 0.5f * (pw - 1.0f);
  float y2 = pcy + 0.5f * (ph - 1.0f);

  float ow = (float)iminfo[1] - 1.0f;
  float oh = (float)iminfo[0] - 1.0f;
  x1 = fminf(fmaxf(x1, 0.0f), ow);
  x2 = fminf(fmaxf(x2, 0.0f), ow);
  y1 = fminf(fmaxf(y1, 0.0f), oh);
  y2 = fminf(fmaxf(y2, 0.0f), oh);

  float ws = x2 - x1 + 1.0f;
  float hs = y2 - y1 + 1.0f;
  bool keep = (score > THRESH_OBJ) && (ws >= 6.0f) && (hs >= 6.0f);

  boxes[r*4+0] = x1;
  boxes[r*4+1] = y1;
  boxes[r*4+2] = x2;
  boxes[r*4+3] = y2;
  mscore[r] = keep ? score : -1.0f;
  if (keep) atomicAdd(cnt, 1);
}

// ---------------- partial rank: grid (i-blocks, j-slices), atomicAdd accumulation ----------------
__global__ __launch_bounds__(256) void k_rank_part(const float* __restrict__ mscore,
    int* __restrict__ rank) {
  constexpr int SLICE = 2176;               // 8 slices * 2176 = 17408 >= 17340
  __shared__ float sm[SLICE];
  int tid = threadIdx.x;
  int i = blockIdx.x * 256 + tid;
  int j0 = blockIdx.y * SLICE;
  for (int j = tid; j < SLICE; j += 256) {
    int jj = j0 + j;
    sm[j] = (jj < NB) ? mscore[jj] : -2.0f;
  }
  __syncthreads();
  float mi = (i < NB) ? mscore[i] : -2.0f;
  if (i >= NB || mi <= THRESH_OBJ) return;
  int r = 0;
  const float4* sm4 = (const float4*)sm;
#pragma unroll 4
  for (int j4 = 0; j4 < SLICE / 4; ++j4) {
    float4 v = sm4[j4];                     // uniform address -> LDS broadcast, conflict-free
    int jb = j0 + j4 * 4;
    r += (v.x > mi || (v.x == mi && jb + 0 < i)) ? 1 : 0;
    r += (v.y > mi || (v.y == mi && jb + 1 < i)) ? 1 : 0;
    r += (v.z > mi || (v.z == mi && jb + 2 < i)) ? 1 : 0;
    r += (v.w > mi || (v.w == mi && jb + 3 < i)) ? 1 : 0;
  }
  atomicAdd(&rank[i], r);
}

// ---------------- scatter boxes into sorted order ----------------
__global__ __launch_bounds__(256) void k_scatter(const float* __restrict__ mscore,
    const int* __restrict__ rank, const float* __restrict__ boxes,
    float* __restrict__ sboxes) {
  int i = blockIdx.x * 256 + threadIdx.x;
  if (i >= NB) return;
  if (mscore[i] <= THRESH_OBJ) return;
  int r = rank[i];
  if (r < MAXC) ((float4*)sboxes)[r] = ((const float4*)boxes)[i];
}

// ---------------- pairwise IoU bitmask (full grid; lower triangle writes zeros) ----------------
__global__ __launch_bounds__(64) void k_iou(const float* __restrict__ sboxes,
    const int* __restrict__ cnt, unsigned long long* __restrict__ mask) {
#pragma clang fp contract(off)
  int N = min(*cnt, MAXC);
  int bi = blockIdx.x, bj = blockIdx.y;
  int t = threadIdx.x;
  int i = bi * 64 + t;
  if (bj < bi) {                      // lower triangle: just zero-fill (ws is poisoned)
    if (i < N) mask[(size_t)i * NW64 + bj] = 0ULL;
    return;
  }
  if (bi * 64 >= N) return;
  __shared__ float4 jb[64];
  int j0 = bj * 64;
  if (j0 + t < N) jb[t] = ((const float4*)sboxes)[j0 + t];
  __syncthreads();
  if (i >= N) return;
  float4 a = ((const float4*)sboxes)[i];
  float areaA = (a.z - a.x + 1.0f) * (a.w - a.y + 1.0f);
  unsigned long long word = 0;
  int jmax = min(64, N - j0);
  for (int jj = 0; jj < jmax; ++jj) {
    int j = j0 + jj;
    if (j <= i) continue;
    float4 b = jb[jj];
    float iw = fminf(a.z, b.z) - fmaxf(a.x, b.x) + 1.0f;
    float ih = fminf(a.w, b.w) - fmaxf(a.y, b.y) + 1.0f;
    iw = fmaxf(iw, 0.0f);
    ih = fmaxf(ih, 0.0f);
    float inter = iw * ih;
    float areaB = (b.z - b.x + 1.0f) * (b.w - b.y + 1.0f);
    float iou = inter / (areaA + areaB - inter);
    if (iou > NMS_T) word |= (1ULL << jj);
  }
  mask[(size_t)i * NW64 + bj] = word;
}

// ---------------- serial greedy NMS: register remv, shfl broadcast, 4-deep prefetch ----------------
__global__ __launch_bounds__(64) void k_nms(const float* __restrict__ sboxes,
    const unsigned long long* __restrict__ mask, const int* __restrict__ cnt,
    float* __restrict__ out) {
  int t = threadIdx.x;
  int N = min(*cnt, MAXC);
  unsigned long long r0 = 0ULL, r1 = 0ULL;   // remv words t and t+64 (t+64 valid for t<15)
  __shared__ int klist[TOPN];
  constexpr int D = 4;
  unsigned long long pa[D], pb[D];
#pragma unroll
  for (int d = 0; d < D; ++d) {
    const unsigned long long* row = mask + (size_t)d * NW64;
    bool ok = d < N;
    pa[d] = ok ? row[t] : 0ULL;
    pb[d] = (ok && t + 64 < NW64) ? row[t + 64] : 0ULL;
  }
  int kept = 0;
  for (int i0 = 0; i0 < N; i0 += D) {
    if (kept >= TOPN) break;
#pragma unroll
    for (int d = 0; d < D; ++d) {
      int i = i0 + d;
      if (i < N && kept < TOPN) {
        int w = i >> 6;                      // uniform
        unsigned long long sel = (w < 64) ? r0 : r1;
        unsigned long long wv = __shfl(sel, w & 63, 64);
        if (!((wv >> (i & 63)) & 1ULL)) {
          if (t == 0) klist[kept] = i;
          r0 |= pa[d];
          r1 |= pb[d];
          ++kept;
        }
        int ip = i + D;                      // prefetch D ahead
        const unsigned long long* rowp = mask + (size_t)ip * NW64;
        bool ok = ip < N;
        pa[d] = ok ? rowp[t] : 0ULL;
        pb[d] = (ok && t + 64 < NW64) ? rowp[t + 64] : 0ULL;
      }
    }
  }
  __syncthreads();
  // parallel output write: 16 rows per pass, 4 lanes per row
  int rr = t >> 2, cc = t & 3;
  for (int k = rr; k < kept; k += 16) {
    int idx = klist[k];
    out[k * 5 + 1 + cc] = sboxes[idx * 4 + cc];
  }
}

extern "C" void kernel_launch(void* const* d_in, const int* in_sizes, int n_in,
                              void* d_out, int out_size, void* d_ws, size_t ws_size,
                              hipStream_t stream) {
  const float* cls  = (const float*)d_in[0];
  const float* pred = (const float*)d_in[1];
  const int*   imi  = (const int*)d_in[2];
  const float* mean = (const float*)d_in[3];
  const float* stdv = (const float*)d_in[4];
  float* out = (float*)d_out;

  char* ws = (char*)d_ws;
  float* boxes  = (float*)(ws);                        // NB*4 floats   = 277440 B
  float* mscore = (float*)(ws + 277440);               // NB floats     = 69360 B
  float* sboxes = (float*)(ws + 346800);               // MAXC*4 floats = 80000 B
  int*   cnt    = (int*)(ws + 426800);                 // 4 B (+pad)
  int*   rank   = (int*)(ws + 426816);                 // NB ints       = 69360 B
  unsigned long long* mask = (unsigned long long*)(ws + 496192); // MAXC*NW64*8 = 3160000 B

  hipMemsetAsync(cnt, 0, sizeof(int), stream);
  hipMemsetAsync(d_out, 0, (size_t)out_size * sizeof(float), stream);

  k_decode<<<(NB + 255) / 256, 256, 0, stream>>>(cls, pred, imi, mean, stdv, boxes, mscore, cnt, rank);
  dim3 grank((NB + 255) / 256, 8);
  k_rank_part<<<grank, 256, 0, stream>>>(mscore, rank);
  k_scatter<<<(NB + 255) / 256, 256, 0, stream>>>(mscore, rank, boxes, sboxes);
  dim3 giou(NW64, NW64);
  k_iou<<<giou, 64, 0, stream>>>(sboxes, cnt, mask);
  k_nms<<<1, 64, 0, stream>>>(sboxes, mask, cnt, out);
}